// Round 7
// baseline (492.405 us; speedup 1.0000x reference)
//
#include <hip/hip_runtime.h>
#include <math.h>

#define BB 16384
#define DD 4096
#define EE 64
#define TK 8
#define RT 32            // rows per block; grid = 512 -> 2 blocks/CU

typedef __attribute__((ext_vector_type(8))) short s16x8;
typedef __attribute__((ext_vector_type(4))) float f32x4;

__device__ inline unsigned pack_hi2(float a, float b) {
    return (__float_as_uint(a) >> 16) | (__float_as_uint(b) & 0xFFFF0000u);
}
__device__ inline float hi_part(float a) {
    return __uint_as_float(__float_as_uint(a) & 0xFFFF0000u);
}
__device__ inline void split_pack(const float4& v0, const float4& v1, uint4& h, uint4& l) {
    h.x = pack_hi2(v0.x, v0.y); h.y = pack_hi2(v0.z, v0.w);
    h.z = pack_hi2(v1.x, v1.y); h.w = pack_hi2(v1.z, v1.w);
    l.x = pack_hi2(v0.x - hi_part(v0.x), v0.y - hi_part(v0.y));
    l.y = pack_hi2(v0.z - hi_part(v0.z), v0.w - hi_part(v0.w));
    l.z = pack_hi2(v1.x - hi_part(v1.x), v1.y - hi_part(v1.y));
    l.w = pack_hi2(v1.z - hi_part(v1.z), v1.w - hi_part(v1.w));
}

// ---------------------------------------------------------------------------
// prep: [wg | wn] fp32 -> bf16 hi/lo in MFMA B-fragment order (verified r2-6).
// ws layout: [kchunk64(64)][sub(2)][prec(2)][ntile(8)][lane(64)][16B]
// A 32-k chunk ch uses the contiguous 16 KB at kc*32768 + (ch&1)*16384.
// ---------------------------------------------------------------------------
__global__ __launch_bounds__(256, 1)
void prep_w(const float* __restrict__ wg, const float* __restrict__ wn,
            char* __restrict__ wsB)
{
    __shared__ float Wtmp[64 * 132];
    const int t  = threadIdx.x;
    const int kc = blockIdx.x;

#pragma unroll
    for (int i = 0; i < 8; ++i) {
        int fid = t + i * 256;
        int m   = fid >> 10;
        int id  = fid & 1023;
        int kk  = id >> 4;
        int n4  = id & 15;
        const float* src = (m ? wn : wg) + (size_t)(kc * 64 + kk) * EE + n4 * 4;
        float4 v = *(const float4*)src;
        *(float4*)&Wtmp[kk * 132 + m * 64 + n4 * 4] = v;
    }
    __syncthreads();

#pragma unroll
    for (int i = 0; i < 4; ++i) {
        int id  = t + i * 256;
        int sub = id >> 9;
        int nt  = (id >> 6) & 7;
        int ln  = id & 63;
        int n   = nt * 16 + (ln & 15);
        int k0  = sub * 32 + (ln >> 4) * 8;
        float f[8];
#pragma unroll
        for (int j = 0; j < 8; ++j) f[j] = Wtmp[(k0 + j) * 132 + n];
        uint4 h, l;
        h.x = pack_hi2(f[0], f[1]); h.y = pack_hi2(f[2], f[3]);
        h.z = pack_hi2(f[4], f[5]); h.w = pack_hi2(f[6], f[7]);
        l.x = pack_hi2(f[0] - hi_part(f[0]), f[1] - hi_part(f[1]));
        l.y = pack_hi2(f[2] - hi_part(f[2]), f[3] - hi_part(f[3]));
        l.z = pack_hi2(f[4] - hi_part(f[4]), f[5] - hi_part(f[5]));
        l.w = pack_hi2(f[6] - hi_part(f[6]), f[7] - hi_part(f[7]));
        size_t base = (size_t)kc * 32768;
        *(uint4*)(wsB + base + (size_t)(((sub * 2 + 0) * 8 + nt) * 64 + ln) * 16) = h;
        *(uint4*)(wsB + base + (size_t)(((sub * 2 + 1) * 8 + nt) * 64 + ln) * 16) = l;
    }
}

// ---------------------------------------------------------------------------
// main: 512 blocks x 256 threads (4 waves), 2 blocks/CU. Block = 32 rows x
// 128 cols x full K; chunk = 32 k (128 chunks). Wave tile 32m x 32n (wave w
// owns n-quarter w) -> B read with zero duplication, A broadcast to all waves.
// BOTH operands staged via global_load_lds (no data VGPRs -> no WAW register
// serialization, the r3-r6 killer). Double-buffered; DMA(ch+1) issued right
// after the barrier, drained one full compute interval later.
// A LDS layout: slot idx = tid = mt*128 + q*32 + h*16 + m16 (16 B each);
// consumer lane reads 16 B lane-contiguous -> conflict-free.
// ---------------------------------------------------------------------------
__global__ __launch_bounds__(256, 2)
void moe_mfma(const float* __restrict__ x,
              const float* __restrict__ noise,
              const char* __restrict__ wsB,
              float* __restrict__ gates,
              float* __restrict__ load)
{
    __shared__ char  smem[2 * 4096 + 2 * 16384];   // A0 A1 B0 B1 = 40 KB
    __shared__ float red[256];
    char* const Ab0 = smem;
    char* const Ab1 = smem + 4096;
    char* const Bb0 = smem + 8192;
    char* const Bb1 = smem + 8192 + 16384;

    const int tid  = threadIdx.x;
    const int w    = tid >> 6;
    const int lane = tid & 63;
    const int rb   = blockIdx.x * RT;

    // ---- A DMA source (per-lane gather, 64B-per-row segments) ----
    // tid = mt*128 + q*32 + h*16 + m16 : row rb+mt*16+m16, k = q*8+h*4
    const int mt_s = tid >> 7;
    const int q_s  = (tid >> 5) & 3;
    const int h_s  = (tid >> 4) & 1;
    const int m_s  = tid & 15;
    const float* xa = x + (size_t)(rb + mt_s * 16 + m_s) * DD + q_s * 8 + h_s * 4;
    const int aslot = (tid >> 6) * 1024;           // wave-uniform LDS base offset

    f32x4 acc[2][2];
#pragma unroll
    for (int mt = 0; mt < 2; ++mt)
#pragma unroll
        for (int nt = 0; nt < 2; ++nt) acc[mt][nt] = (f32x4){0.f, 0.f, 0.f, 0.f};

    auto issueA = [&](int ch, char* Ab) {
        __builtin_amdgcn_global_load_lds(
            (const __attribute__((address_space(1))) unsigned int*)(xa + ch * 32),
            (__attribute__((address_space(3))) unsigned int*)(Ab + aslot),
            16, 0, 0);
    };
    auto issueB = [&](int ch, char* Bb) {
        const char* gB = wsB + (size_t)(ch >> 1) * 32768 + (size_t)(ch & 1) * 16384;
#pragma unroll
        for (int i = 0; i < 4; ++i) {
            const int si = w * 4 + i;
            __builtin_amdgcn_global_load_lds(
                (const __attribute__((address_space(1))) unsigned int*)(gB + (size_t)si * 1024 + lane * 16),
                (__attribute__((address_space(3))) unsigned int*)(Bb + si * 1024),
                16, 0, 0);
        }
    };
    auto compute = [&](const char* Ab, const char* Bb) {
        const int q = lane >> 4, m16 = lane & 15;
#pragma unroll
        for (int mt = 0; mt < 2; ++mt) {
            const char* ab = Ab + (mt * 128 + q * 32 + m16) * 16;
            const float4 v0 = *(const float4*)ab;
            const float4 v1 = *(const float4*)(ab + 256);
            uint4 h, l;
            split_pack(v0, v1, h, l);
            const s16x8 ah = __builtin_bit_cast(s16x8, h);
            const s16x8 al = __builtin_bit_cast(s16x8, l);
#pragma unroll
            for (int nt = 0; nt < 2; ++nt) {
                const s16x8 bh = *(const s16x8*)(Bb + (((0 * 8) + w * 2 + nt) * 64 + lane) * 16);
                const s16x8 bl = *(const s16x8*)(Bb + (((1 * 8) + w * 2 + nt) * 64 + lane) * 16);
                acc[mt][nt] = __builtin_amdgcn_mfma_f32_16x16x32_bf16(ah, bh, acc[mt][nt], 0, 0, 0);
                acc[mt][nt] = __builtin_amdgcn_mfma_f32_16x16x32_bf16(ah, bl, acc[mt][nt], 0, 0, 0);
                acc[mt][nt] = __builtin_amdgcn_mfma_f32_16x16x32_bf16(al, bh, acc[mt][nt], 0, 0, 0);
            }
        }
    };

    issueA(0, Ab0);
    issueB(0, Bb0);

    for (int ch = 0; ch < 128; ch += 2) {
        __syncthreads();                 // DMA(ch)->buf0 landed (issued 1 interval ago)
        issueA(ch + 1, Ab1);
        issueB(ch + 1, Bb1);
        __builtin_amdgcn_sched_barrier(0);
        compute(Ab0, Bb0);
        __syncthreads();                 // DMA(ch+1)->buf1 landed
        if (ch + 2 < 128) {
            issueA(ch + 2, Ab0);
            issueB(ch + 2, Bb0);
        }
        __builtin_amdgcn_sched_barrier(0);
        compute(Ab1, Bb1);
    }

    // ---- epilogue: logits tile overlaid on smem ----
    __syncthreads();
    float* Ls = (float*)smem;            // 32 x 132 x 4 = 16896 B < 40960
    const int q4 = lane >> 4, cc = lane & 15;
#pragma unroll
    for (int mt = 0; mt < 2; ++mt)
#pragma unroll
        for (int nt = 0; nt < 2; ++nt)
#pragma unroll
            for (int r = 0; r < 4; ++r)
                Ls[(mt * 16 + q4 * 4 + r) * 132 + w * 32 + nt * 16 + cc] = acc[mt][nt][r];
    __syncthreads();

    // ---- fused epilogue (verified r1-6): wave-per-row, lane = expert ----
    float loadAcc = 0.f;
    for (int rr = 0; rr < 8; ++rr) {
        const int row = w * 8 + rr;
        const float clean = Ls[row * 132 + lane];
        const float rawn  = Ls[row * 132 + 64 + lane];
        const float nz    = noise[(size_t)(rb + row) * EE + lane];

        const float sp = fmaxf(rawn, 0.f) + log1pf(expf(-fabsf(rawn)));
        const float sd = sp + 0.01f;
        const float noisy = clean + nz * sd;

        float m = noisy;
#pragma unroll
        for (int off = 32; off; off >>= 1) m = fmaxf(m, __shfl_xor(m, off));
        const float ex = expf(noisy - m);
        float s = ex;
#pragma unroll
        for (int off = 32; off; off >>= 1) s += __shfl_xor(s, off);
        const float p = ex / s;

        float cur = p;
        int selrank = -1;
        float v[9];
#pragma unroll
        for (int j = 0; j < 9; ++j) {
            float bv = cur;
            int   bi = lane;
#pragma unroll
            for (int off = 32; off; off >>= 1) {
                const float ov = __shfl_xor(bv, off);
                const int   oi = __shfl_xor(bi, off);
                if (ov > bv || (ov == bv && oi < bi)) { bv = ov; bi = oi; }
            }
            v[j] = bv;
            if (lane == bi) { cur = -1.f; if (j < TK) selrank = j; }
        }

        float denom = 0.f;
#pragma unroll
        for (int j = 0; j < TK; ++j) denom += expf(v[j] - v[0]);
        const float gate = (selrank >= 0) ? (expf(p - v[0]) / denom) : 0.f;
        gates[(size_t)(rb + row) * EE + lane] = gate;

        const float thr_in  = v[8];
        const float thr_out = v[7];
        const bool  is_in   = noisy > thr_in;
        const float a = (clean - (is_in ? thr_in : thr_out)) / sd;
        loadAcc += 0.5f * (1.f + erff(a * 0.70710678118654752f));
    }

    red[w * 64 + lane] = loadAcc;
    __syncthreads();
    if (tid < 64) {
        const float s = red[tid] + red[64 + tid] + red[128 + tid] + red[192 + tid];
        atomicAdd(&load[tid], s);
    }
}

extern "C" void kernel_launch(void* const* d_in, const int* in_sizes, int n_in,
                              void* d_out, int out_size, void* d_ws, size_t ws_size,
                              hipStream_t stream)
{
    const float* x     = (const float*)d_in[0];
    const float* wg    = (const float*)d_in[1];
    const float* wn    = (const float*)d_in[2];
    const float* noise = (const float*)d_in[3];
    float* gates = (float*)d_out;
    float* load  = (float*)d_out + (size_t)BB * EE;
    char*  wsB   = (char*)d_ws;   // 2 MB

    hipMemsetAsync(load, 0, EE * sizeof(float), stream);
    hipLaunchKernelGGL(prep_w, dim3(DD / 64), dim3(256), 0, stream, wg, wn, wsB);
    hipLaunchKernelGGL(moe_mfma, dim3(BB / RT), dim3(256), 0, stream,
                       x, noise, wsB, gates, load);
}